// Round 10
// baseline (2832.795 us; speedup 1.0000x reference)
//
#include <hip/hip_runtime.h>

#define BB 64
#define TT 512
#define II 256
#define HH 512
#define OO 256

typedef _Float16 f16;
typedef _Float16 half8 __attribute__((ext_vector_type(8)));
typedef _Float16 half4 __attribute__((ext_vector_type(4)));
typedef float f32x4 __attribute__((ext_vector_type(4)));
typedef unsigned long long u64;

#define SENT 0x7C017C017C017C01ull   // 4x f16 NaN — tanh output can never equal this

union U16 { u64 q[2]; half8 h; };
union U8  { u64 q;    half4 h; };

__device__ __forceinline__ u64 llc_load(const f16* p) {
  return __hip_atomic_load((const u64*)p, __ATOMIC_RELAXED, __HIP_MEMORY_SCOPE_SYSTEM);
}
__device__ __forceinline__ void llc_store(f16* p, u64 v) {
  __hip_atomic_store((u64*)p, v, __ATOMIC_RELAXED, __HIP_MEMORY_SCOPE_SYSTEM);
}
__device__ __forceinline__ float ftanh(float x) {
  float e = __expf(2.0f * x);          // v_exp_f32 path; inf/0 saturate correctly
  return 1.0f - 2.0f / (e + 1.0f);
}

// ---------------- prep: fill ys0+h1h with sentinel ----------------
__global__ void prep_sent(u64* __restrict__ dst, size_t n) {
  size_t tid = (size_t)blockIdx.x * blockDim.x + threadIdx.x;
  size_t stride = (size_t)gridDim.x * blockDim.x;
  for (size_t i = tid; i < n; i += stride) dst[i] = SENT;
}

// ---------------- prep: transpose x to time-major fp16 ----------------
__global__ void prep_x(const float* __restrict__ x, f16* __restrict__ xt) {
  size_t tid = (size_t)blockIdx.x * blockDim.x + threadIdx.x;
  size_t stride = (size_t)gridDim.x * blockDim.x;
  size_t nv = (size_t)TT * BB * II / 4;
  for (size_t v = tid; v < nv; v += stride) {
    size_t i = v * 4;
    size_t t = i >> 14;        // / (BB*II)
    size_t rem = i & 16383;
    size_t b = rem >> 8;       // / II
    size_t ii = rem & 255;
    float4 f = *(const float4*)(x + b * (size_t)(TT * II) + t * II + ii);
    half4 h;
    h.x = (f16)f.x; h.y = (f16)f.y; h.z = (f16)f.z; h.w = (f16)f.w;
    *(half4*)(xt + i) = h;
  }
}

// ---------------- prep: weights fp32 -> fp16, bias sums ----------------
__global__ void prep_w(const float* __restrict__ wih0, const float* __restrict__ whh0,
                       const float* __restrict__ wih1, const float* __restrict__ whh1,
                       const float* __restrict__ bih0, const float* __restrict__ bhh0,
                       const float* __restrict__ bih1, const float* __restrict__ bhh1,
                       f16* __restrict__ o0, f16* __restrict__ o1,
                       f16* __restrict__ o2, f16* __restrict__ o3,
                       float* __restrict__ bs0, float* __restrict__ bs1) {
  const size_t n0 = (size_t)HH * II, n1 = (size_t)HH * HH;
  const size_t total = n0 + 3 * n1 + 2 * HH;
  size_t stride = (size_t)gridDim.x * blockDim.x;
  for (size_t i = (size_t)blockIdx.x * blockDim.x + threadIdx.x; i < total; i += stride) {
    size_t j = i;
    if (j < n0) { o0[j] = (f16)wih0[j]; continue; } j -= n0;
    if (j < n1) { o1[j] = (f16)whh0[j]; continue; } j -= n1;
    if (j < n1) { o2[j] = (f16)wih1[j]; continue; } j -= n1;
    if (j < n1) { o3[j] = (f16)whh1[j]; continue; } j -= n1;
    if (j < HH) { bs0[j] = bih0[j] + bhh0[j]; continue; } j -= HH;
    bs1[j] = bih1[j] + bhh1[j];
  }
}

// ---- issue 32 u64 poll loads (16 half8 A-fragments) ----
__device__ __forceinline__ void issue32(const f16* base, u64* q) {
#pragma unroll
  for (int kf = 0; kf < 16; ++kf) {
    q[2 * kf]     = llc_load(base + kf * 32);
    q[2 * kf + 1] = llc_load(base + kf * 32 + 4);
  }
}
// ---- validate in-register values; re-issue until sentinel-free ----
__device__ __forceinline__ void validate32(const f16* base, u64* q) {
  for (int it = 0; it < 200000; ++it) {
    int ok = 1;
#pragma unroll
    for (int i = 0; i < 32; ++i) ok &= (q[i] != SENT);
    if (__all(ok)) return;
    issue32(base, q);
  }
}
__device__ __forceinline__ half8 frag(const u64* q, int kf) {
  U16 u; u.q[0] = q[2 * kf]; u.q[1] = q[2 * kf + 1];
  return u.h;
}

// ---- fence-free pipelined 2-layer RNN: 256 waves = 2 layers x 4 clusters x 16-col slices ----
// Weights live in LDS (staged once); per-step ds_read_b128, never L2.
__global__ __launch_bounds__(64, 1) void rnn_seq(
    const f16* __restrict__ xt, f16* __restrict__ ys0, f16* __restrict__ h1h,
    const f16* __restrict__ wih0, const f16* __restrict__ whh0,
    const f16* __restrict__ wih1, const f16* __restrict__ whh1,
    const float* __restrict__ bs0, const float* __restrict__ bs1,
    const float* __restrict__ wfc, const float* __restrict__ bfc,
    float* __restrict__ out) {
  const int wg = blockIdx.x;        // 0..255
  const int layer = wg >> 7;        // 0/1
  const int c = (wg >> 5) & 3;      // batch cluster (rows c*16..+15)
  const int s = wg & 31;            // H-slice (cols s*16..+15)
  const int lane = threadIdx.x;
  const int fr = lane & 15;
  const int kg = lane >> 4;         // 0..3
  const int n0 = s * 16;

  __shared__ f16 wlds[32 * 64 * 8]; // weight fragments: [frag_slot][lane] x 8 halfs (32 KB)
  __shared__ f16 tile[16 * 16];     // one wave's 16x16 output tile (512 B)

  // per-lane LDS frag accessor: slot kf, own lane entry
  auto ldsw = [&](int slot) -> half8 {
    return *(const half8*)(wlds + ((size_t)(slot * 64 + lane)) * 8);
  };

  if (layer == 0) {
    // ---- stage weights: slots 0..7 = W_ih0 (K=256), 8..23 = W_hh0 (K=512) ----
    {
      const f16* wi = wih0 + (size_t)(n0 + fr) * II + kg * 8;
#pragma unroll
      for (int kf = 0; kf < 8; ++kf)
        *(half8*)(wlds + (size_t)(kf * 64 + lane) * 8) = *(const half8*)(wi + kf * 32);
      const f16* wh = whh0 + (size_t)(n0 + fr) * HH + kg * 8;
#pragma unroll
      for (int kf = 0; kf < 16; ++kf)
        *(half8*)(wlds + (size_t)((8 + kf) * 64 + lane) * 8) = *(const half8*)(wh + kf * 32);
    }
    __syncthreads();
    const float bias = bs0[n0 + fr];
    // x-projection for t=0
    f32x4 pA = {0,0,0,0}, pB = {0,0,0,0};
    {
      const f16* xa = xt + ((size_t)0 * BB + c * 16 + fr) * II + kg * 8;
#pragma unroll
      for (int kf = 0; kf < 8; kf += 2) {
        pA = __builtin_amdgcn_mfma_f32_16x16x32_f16(*(const half8*)(xa + kf * 32), ldsw(kf), pA, 0, 0, 0);
        pB = __builtin_amdgcn_mfma_f32_16x16x32_f16(*(const half8*)(xa + (kf + 1) * 32), ldsw(kf + 1), pB, 0, 0, 0);
      }
    }
    for (int t = 0; t < TT; ++t) {
      f32x4 aA = pA, aB = pB;
      if (t > 0) {
        const f16* hb = ys0 + ((size_t)(t - 1) * BB + c * 16 + fr) * HH + kg * 8;
        u64 q[32];
        issue32(hb, q);
        validate32(hb, q);
#pragma unroll
        for (int kf = 0; kf < 16; kf += 2) {
          aA = __builtin_amdgcn_mfma_f32_16x16x32_f16(frag(q, kf), ldsw(8 + kf), aA, 0, 0, 0);
          aB = __builtin_amdgcn_mfma_f32_16x16x32_f16(frag(q, kf + 1), ldsw(9 + kf), aB, 0, 0, 0);
        }
      }
      f32x4 acc = aA + aB;
      __syncthreads();   // WAR guard on tile
#pragma unroll
      for (int r = 0; r < 4; ++r)
        tile[(kg * 4 + r) * 16 + fr] = (f16)ftanh(acc[r] + bias);
      __syncthreads();
      {
        u64 w = *(const u64*)(tile + (lane >> 2) * 16 + (lane & 3) * 4);
        llc_store(ys0 + ((size_t)t * BB + c * 16 + (lane >> 2)) * HH + n0 + (lane & 3) * 4, w);
      }
      // off critical path: x-projection for t+1
      if (t + 1 < TT) {
        pA = (f32x4){0,0,0,0}; pB = (f32x4){0,0,0,0};
        const f16* xa = xt + ((size_t)(t + 1) * BB + c * 16 + fr) * II + kg * 8;
#pragma unroll
      for (int kf = 0; kf < 8; kf += 2) {
          pA = __builtin_amdgcn_mfma_f32_16x16x32_f16(*(const half8*)(xa + kf * 32), ldsw(kf), pA, 0, 0, 0);
          pB = __builtin_amdgcn_mfma_f32_16x16x32_f16(*(const half8*)(xa + (kf + 1) * 32), ldsw(kf + 1), pB, 0, 0, 0);
        }
      }
    }
  } else {
    // ---- stage weights: slots 0..15 = W_ih1, 16..31 = W_hh1 (both K=512) ----
    {
      const f16* wi = wih1 + (size_t)(n0 + fr) * HH + kg * 8;
#pragma unroll
      for (int kf = 0; kf < 16; ++kf)
        *(half8*)(wlds + (size_t)(kf * 64 + lane) * 8) = *(const half8*)(wi + kf * 32);
      const f16* wh = whh1 + (size_t)(n0 + fr) * HH + kg * 8;
#pragma unroll
      for (int kf = 0; kf < 16; ++kf)
        *(half8*)(wlds + (size_t)((16 + kf) * 64 + lane) * 8) = *(const half8*)(wh + kf * 32);
    }
    __syncthreads();
    const float bias = bs1[n0 + fr];
    for (int t = 0; t < TT; ++t) {
      // issue recurrence poll loads FIRST (overlap with input processing)
      const f16* hb = h1h + ((size_t)(t - 1) * BB + c * 16 + fr) * HH + kg * 8;
      u64 qh[32];
      if (t > 0) issue32(hb, qh);
      // input from ys0[t] (lags layer-0 producer by >=1 step)
      const f16* ib = ys0 + ((size_t)t * BB + c * 16 + fr) * HH + kg * 8;
      u64 qi[32];
      issue32(ib, qi);
      validate32(ib, qi);
      f32x4 aA = {0,0,0,0}, aB = {0,0,0,0};
#pragma unroll
      for (int kf = 0; kf < 16; kf += 2) {
        aA = __builtin_amdgcn_mfma_f32_16x16x32_f16(frag(qi, kf), ldsw(kf), aA, 0, 0, 0);
        aB = __builtin_amdgcn_mfma_f32_16x16x32_f16(frag(qi, kf + 1), ldsw(kf + 1), aB, 0, 0, 0);
      }
      if (t > 0) {
        validate32(hb, qh);
#pragma unroll
        for (int kf = 0; kf < 16; kf += 2) {
          aA = __builtin_amdgcn_mfma_f32_16x16x32_f16(frag(qh, kf), ldsw(16 + kf), aA, 0, 0, 0);
          aB = __builtin_amdgcn_mfma_f32_16x16x32_f16(frag(qh, kf + 1), ldsw(17 + kf), aB, 0, 0, 0);
        }
      }
      f32x4 acc = aA + aB;
      __syncthreads();
#pragma unroll
      for (int r = 0; r < 4; ++r)
        tile[(kg * 4 + r) * 16 + fr] = (f16)ftanh(acc[r] + bias);
      __syncthreads();
      {
        u64 w = *(const u64*)(tile + (lane >> 2) * 16 + (lane & 3) * 4);
        llc_store(h1h + ((size_t)t * BB + c * 16 + (lane >> 2)) * HH + n0 + (lane & 3) * 4, w);
      }
    }
    // ========= final FC: out[row][col0..col0+1], full K=512 in 8 validated chunks =========
    {
      const int row = c * 16 + fr;        // batch row
      const int col0 = s * 8 + kg * 2;    // two output cols per lane
      const f16* hb = h1h + ((size_t)(TT - 1) * BB + row) * HH;
      float r0 = bfc[col0], r1 = bfc[col0 + 1];
      const float4* w0 = (const float4*)(wfc + (size_t)(col0 + 0) * HH);
      const float4* w1 = (const float4*)(wfc + (size_t)(col0 + 1) * HH);
      for (int ch = 0; ch < 8; ++ch) {      // 8 chunks x 16 u64 = 512 f16
        u64 q[16];
        for (int iter = 0; iter < 200000; ++iter) {
#pragma unroll
          for (int i = 0; i < 16; ++i) q[i] = llc_load(hb + (ch * 16 + i) * 4);
          int ok = 1;
#pragma unroll
          for (int i = 0; i < 16; ++i) ok &= (q[i] != SENT);
          if (__all(ok)) break;
        }
#pragma unroll
        for (int i = 0; i < 16; ++i) {
          U8 u; u.q = q[i];
          int bi = ch * 16 + i;
          float h0 = (float)u.h.x, h1 = (float)u.h.y, h2 = (float)u.h.z, h3 = (float)u.h.w;
          float4 a = w0[bi], b = w1[bi];
          r0 += h0 * a.x + h1 * a.y + h2 * a.z + h3 * a.w;
          r1 += h0 * b.x + h1 * b.y + h2 * b.z + h3 * b.w;
        }
      }
      out[(size_t)row * OO + col0] = r0;
      out[(size_t)row * OO + col0 + 1] = r1;
    }
  }
}

extern "C" void kernel_launch(void* const* d_in, const int* in_sizes, int n_in,
                              void* d_out, int out_size, void* d_ws, size_t ws_size,
                              hipStream_t stream) {
  const float* x    = (const float*)d_in[0];
  const float* wih0 = (const float*)d_in[1];
  const float* whh0 = (const float*)d_in[2];
  const float* bih0 = (const float*)d_in[3];
  const float* bhh0 = (const float*)d_in[4];
  const float* wih1 = (const float*)d_in[5];
  const float* whh1 = (const float*)d_in[6];
  const float* bih1 = (const float*)d_in[7];
  const float* bhh1 = (const float*)d_in[8];
  const float* wfc  = (const float*)d_in[9];
  const float* bfc  = (const float*)d_in[10];
  float* out = (float*)d_out;

  char* base = (char*)d_ws;
  size_t off = 0;
  auto take = [&](size_t bytes) {
    char* r = base + off;
    off = (off + bytes + 255) & ~(size_t)255;
    return r;
  };
  f16* xt      = (f16*)take((size_t)TT * BB * II * 2);   // 16.8 MB
  f16* ys0     = (f16*)take((size_t)TT * BB * HH * 2);   // 33.6 MB
  f16* h1h     = (f16*)take((size_t)TT * BB * HH * 2);   // 33.6 MB (contiguous with ys0)
  f16* fwih0   = (f16*)take((size_t)HH * II * 2);
  f16* fwhh0   = (f16*)take((size_t)HH * HH * 2);
  f16* fwih1   = (f16*)take((size_t)HH * HH * 2);
  f16* fwhh1   = (f16*)take((size_t)HH * HH * 2);
  float* bs0   = (float*)take(HH * 4);
  float* bs1   = (float*)take(HH * 4);
  (void)ws_size; (void)in_sizes; (void)n_in; (void)out_size;

  // sentinel-fill both history buffers (contiguous)
  size_t n_u64 = (size_t)2 * TT * BB * HH / 4;
  prep_sent<<<dim3(2048), dim3(256), 0, stream>>>((u64*)ys0, n_u64);
  prep_x<<<dim3(1024), dim3(256), 0, stream>>>(x, xt);
  prep_w<<<dim3(512), dim3(256), 0, stream>>>(wih0, whh0, wih1, whh1,
                                              bih0, bhh0, bih1, bhh1,
                                              fwih0, fwhh0, fwih1, fwhh1, bs0, bs1);

  rnn_seq<<<dim3(256), dim3(64), 0, stream>>>(xt, ys0, h1h,
                                              fwih0, fwhh0, fwih1, fwhh1,
                                              bs0, bs1, wfc, bfc, out);
}